// Round 1
// baseline (621.929 us; speedup 1.0000x reference)
//
#include <hip/hip_runtime.h>

typedef __bf16 bf16;
typedef bf16 bf16x8 __attribute__((ext_vector_type(8)));
typedef float f32x4 __attribute__((ext_vector_type(4)));
typedef unsigned int u32x4 __attribute__((ext_vector_type(4)));
typedef unsigned short u16x8 __attribute__((ext_vector_type(8)));
typedef unsigned int uint;

constexpr int NT = 4096;   // sequence length N
// H = 64, B = 2

__device__ __forceinline__ bf16x8 ld8f(const float* p) {
    f32x4 a = *(const f32x4*)p;
    f32x4 b = *(const f32x4*)(p + 4);
    bf16x8 v;
    v[0] = (bf16)a[0]; v[1] = (bf16)a[1]; v[2] = (bf16)a[2]; v[3] = (bf16)a[3];
    v[4] = (bf16)b[0]; v[5] = (bf16)b[1]; v[6] = (bf16)b[2]; v[7] = (bf16)b[3];
    return v;
}

__device__ __forceinline__ uint pack2(float a, float b) {
    unsigned short ua = __builtin_bit_cast(unsigned short, (bf16)a);
    unsigned short ub = __builtin_bit_cast(unsigned short, (bf16)b);
    return (uint)ua | ((uint)ub << 16);
}

// ---------------------------------------------------------------------------
// Kernel 1: projections q_t = norm(h_t @ Wq[t]^T), k_e = norm(h_pred @ Wk[e]^T)
// (bf16 out), plus vT[p][b][h][n] = bf16 transpose of h_p.
// Block: 256 thr = 4 waves, 64 rows of B*N per block. grid = 8192/64 = 128.
// MFMA 16x16x32 bf16: A row = lane&15, k = quad*8+j; C col=lane&15, row=quad*4+reg.
// ---------------------------------------------------------------------------
__global__ __launch_bounds__(256) void prep_kernel(
    const float* __restrict__ h0, const float* __restrict__ h1, const float* __restrict__ h2,
    const float* __restrict__ Wq, const float* __restrict__ Wk,
    bf16* __restrict__ qn, bf16* __restrict__ kn, bf16* __restrict__ vT)
{
    __shared__ __align__(16) unsigned short tlds[4][16][72];
    const int tid = threadIdx.x, wid = tid >> 6, lane = tid & 63;
    const int l15 = lane & 15, quad = lane >> 4;
    const int g0 = blockIdx.x * 64;
    const int grow = g0 + wid * 16 + l15;     // A-frag row (global b*N+n)
    const float* hs[3] = {h0, h1, h2};

    // A-fragments: h rows in bf16 (also the vT payload)
    bf16x8 af[3][2];
#pragma unroll
    for (int p = 0; p < 3; p++)
#pragma unroll
        for (int hc = 0; hc < 2; hc++)
            af[p][hc] = ld8f(hs[p] + (size_t)grow * 64 + hc * 32 + quad * 8);

    // ---- vT: transpose via per-wave LDS tile ----
    const int gr0 = g0 + wid * 16;
    const int bb = gr0 >> 12, n0 = gr0 & 4095;
#pragma unroll
    for (int p = 0; p < 3; p++) {
#pragma unroll
        for (int hc = 0; hc < 2; hc++)
            *(u16x8*)(&tlds[wid][l15][hc * 32 + quad * 8]) = __builtin_bit_cast(u16x8, af[p][hc]);
        unsigned short vals[16];
#pragma unroll
        for (int r = 0; r < 16; r++) vals[r] = tlds[wid][r][lane];
        uint us[8];
#pragma unroll
        for (int k = 0; k < 8; k++) us[k] = (uint)vals[2 * k] | ((uint)vals[2 * k + 1] << 16);
        uint* dst = (uint*)(vT + ((size_t)(p * 2 + bb) * 64 + lane) * NT + n0);
        u32x4 w0 = {us[0], us[1], us[2], us[3]};
        u32x4 w1 = {us[4], us[5], us[6], us[7]};
        *(u32x4*)dst = w0;
        *(u32x4*)(dst + 4) = w1;
    }

    // ---- 9 projections: 0..2 = q (src = type), 3..8 = k (src = pred[e]) ----
    const int predmap[6] = {0, 2, 0, 1, 1, 2};
#pragma unroll
    for (int pj = 0; pj < 9; pj++) {
        const float* W = (pj < 3) ? (Wq + pj * 4096) : (Wk + (pj - 3) * 4096);
        const int src = (pj < 3) ? pj : predmap[pj - 3];
        bf16* outp = (pj < 3) ? (qn + (size_t)pj * 2 * NT * 64)
                              : (kn + (size_t)(pj - 3) * 2 * NT * 64);
        f32x4 s[4];
#pragma unroll
        for (int it = 0; it < 4; it++) {
            f32x4 acc = {0.f, 0.f, 0.f, 0.f};
#pragma unroll
            for (int hc = 0; hc < 2; hc++) {
                bf16x8 wb = ld8f(W + (size_t)(it * 16 + l15) * 64 + hc * 32 + quad * 8);
                acc = __builtin_amdgcn_mfma_f32_16x16x32_bf16(af[src][hc], wb, acc, 0, 0, 0);
            }
            s[it] = acc;
        }
        // row-wise normalization (fp32): row = quad*4 + r; reduce over 16 col-lanes
#pragma unroll
        for (int r = 0; r < 4; r++) {
            float ss = s[0][r] * s[0][r] + s[1][r] * s[1][r] + s[2][r] * s[2][r] + s[3][r] * s[3][r];
            ss += __shfl_xor(ss, 1); ss += __shfl_xor(ss, 2);
            ss += __shfl_xor(ss, 4); ss += __shfl_xor(ss, 8);
            float rn = rsqrtf(ss);
            s[0][r] *= rn; s[1][r] *= rn; s[2][r] *= rn; s[3][r] *= rn;
        }
        const int rowbase = g0 + wid * 16 + quad * 4;
#pragma unroll
        for (int it = 0; it < 4; it++)
#pragma unroll
            for (int r = 0; r < 4; r++)
                outp[(size_t)(rowbase + r) * 64 + it * 16 + l15] = (bf16)s[it][r];
    }
}

// ---------------------------------------------------------------------------
// Kernel 2: masked cosine attention, unscaled partials + mask rowsums.
// grid = 6 edges * 32 q-tiles; block = 256 thr (4 waves * 32 q-rows); both
// batches per block so each mask byte is read exactly once.
// Computes S^T = K·Q^T per 64-wide j tile; P^T = mask ⊙ S^T (bf16);
// acc^T += VT·P^T with P^T B-fragments built via ds_bpermute quad shuffle.
// ---------------------------------------------------------------------------
__global__ __launch_bounds__(256, 2) void attn_kernel(
    const bf16* __restrict__ qn, const bf16* __restrict__ kn, const bf16* __restrict__ vT,
    const float* __restrict__ m00, const float* __restrict__ m20, const float* __restrict__ m01,
    const float* __restrict__ m11, const float* __restrict__ m12, const float* __restrict__ m22,
    float* __restrict__ Pacc, float* __restrict__ rsO)
{
    __shared__ __align__(16) bf16 Klds[2][64][72];
    __shared__ __align__(16) bf16 Vlds[2][64][72];
    const int tid = threadIdx.x, wid = tid >> 6, lane = tid & 63;
    const int l15 = lane & 15, quad = lane >> 4;
    const int bx = blockIdx.x, e = bx >> 5, qt = bx & 31;
    const int qrow0 = qt * 128, wstrip = wid * 32;
    const int qtypemap[6] = {0, 0, 1, 1, 2, 2};
    const int predmap[6]  = {0, 2, 0, 1, 1, 2};
    const float* masks[6] = {m00, m20, m01, m11, m12, m22};
    const float* __restrict__ mask = masks[e];
    const int qtv = qtypemap[e], pv = predmap[e];

    // Q fragments (stage-1 B-operand), register resident: [b][mt][hc]
    bf16x8 Qf[2][2][2];
#pragma unroll
    for (int b = 0; b < 2; b++)
#pragma unroll
        for (int mt = 0; mt < 2; mt++)
#pragma unroll
            for (int hc = 0; hc < 2; hc++)
                Qf[b][mt][hc] = *(const bf16x8*)(qn +
                    ((size_t)(qtv * 2 + b) * NT + qrow0 + wstrip + mt * 16 + l15) * 64 +
                    hc * 32 + quad * 8);

    f32x4 acc2[2][4][2];   // [b][ht][mt]  (acc^T: row=h, col=query)
#pragma unroll
    for (int b = 0; b < 2; b++)
#pragma unroll
        for (int ht = 0; ht < 4; ht++)
#pragma unroll
            for (int mt = 0; mt < 2; mt++) {
                f32x4 z = {0.f, 0.f, 0.f, 0.f};
                acc2[b][ht][mt] = z;
            }
    float rsl[2] = {0.f, 0.f};

#pragma unroll 1
    for (int j0 = 0; j0 < NT; j0 += 64) {
        __syncthreads();
        // stage K (kn rows) and VT (vT rows) for both batches
#pragma unroll
        for (int i = 0; i < 4; i++) {
            int u = tid + 256 * i;                 // 0..1023
            int b = u >> 9, jl = (u >> 3) & 63, ch = u & 7;
            *(u32x4*)(&Klds[b][jl][ch * 8]) =
                *(const u32x4*)(kn + ((size_t)(e * 2 + b) * NT + j0 + jl) * 64 + ch * 8);
            *(u32x4*)(&Vlds[b][jl][ch * 8]) =
                *(const u32x4*)(vT + ((size_t)(pv * 2 + b) * 64 + jl) * NT + j0 + ch * 8);
        }
        __syncthreads();

        // mask fragments (shared by both batches): rows=query m, 4 consecutive j per lane
        f32x4 mv[2][4];
#pragma unroll
        for (int mt = 0; mt < 2; mt++)
#pragma unroll
            for (int jt = 0; jt < 4; jt++) {
                mv[mt][jt] = *(const f32x4*)(mask +
                    (size_t)(qrow0 + wstrip + mt * 16 + l15) * NT + j0 + jt * 16 + quad * 4);
                rsl[mt] += mv[mt][jt][0] + mv[mt][jt][1] + mv[mt][jt][2] + mv[mt][jt][3];
            }

#pragma unroll
        for (int b = 0; b < 2; b++) {
            // stage 1: S^T tiles; pack masked result to bf16 pairs
            uint Pd[4][2][2];    // [jt][mt][d] ; d packs j-pair (quad*4+2d, +1)
#pragma unroll
            for (int jt = 0; jt < 4; jt++)
#pragma unroll
                for (int mt = 0; mt < 2; mt++) {
                    f32x4 sc = {0.f, 0.f, 0.f, 0.f};
#pragma unroll
                    for (int hc = 0; hc < 2; hc++) {
                        bf16x8 a = *(const bf16x8*)(&Klds[b][jt * 16 + l15][hc * 32 + quad * 8]);
                        sc = __builtin_amdgcn_mfma_f32_16x16x32_bf16(a, Qf[b][mt][hc], sc, 0, 0, 0);
                    }
                    sc[0] *= mv[mt][jt][0]; sc[1] *= mv[mt][jt][1];
                    sc[2] *= mv[mt][jt][2]; sc[3] *= mv[mt][jt][3];
                    Pd[jt][mt][0] = pack2(sc[0], sc[1]);
                    Pd[jt][mt][1] = pack2(sc[2], sc[3]);
                }

            // build stage-2 B-fragments (P^T) via ds_bpermute:
            // target (quad tq, col n) vgpr v holds j = c*32 + tq*8 + 2v..2v+1
            // source: tile jt = 2c + (tq>>1), lane quad = (tq&1)*2 + (v>>1), dword = v&1
            uint Bf[2][2][4];    // [mt][c][v]
#pragma unroll
            for (int mt = 0; mt < 2; mt++)
#pragma unroll
                for (int c = 0; c < 2; c++)
#pragma unroll
                    for (int v = 0; v < 4; v++) {
                        int srclane = ((((quad & 1) * 2 + (v >> 1)) * 16 + l15) << 2);
                        int lo = __builtin_amdgcn_ds_bpermute(srclane, (int)Pd[2 * c][mt][v & 1]);
                        int hi = __builtin_amdgcn_ds_bpermute(srclane, (int)Pd[2 * c + 1][mt][v & 1]);
                        Bf[mt][c][v] = (quad & 2) ? (uint)hi : (uint)lo;
                    }

            // stage 2: acc^T += VT · P^T
#pragma unroll
            for (int ht = 0; ht < 4; ht++)
#pragma unroll
                for (int c = 0; c < 2; c++) {
                    bf16x8 a = *(const bf16x8*)(&Vlds[b][ht * 16 + l15][c * 32 + quad * 8]);
#pragma unroll
                    for (int mt = 0; mt < 2; mt++) {
                        u32x4 t = {Bf[mt][c][0], Bf[mt][c][1], Bf[mt][c][2], Bf[mt][c][3]};
                        bf16x8 bbv = __builtin_bit_cast(bf16x8, t);
                        acc2[b][ht][mt] =
                            __builtin_amdgcn_mfma_f32_16x16x32_bf16(a, bbv, acc2[b][ht][mt], 0, 0, 0);
                    }
                }
        }
    }

    // store unscaled partials: acc^T C-layout -> rows n, 4 consecutive h per store
#pragma unroll
    for (int b = 0; b < 2; b++)
#pragma unroll
        for (int ht = 0; ht < 4; ht++)
#pragma unroll
            for (int mt = 0; mt < 2; mt++) {
                int row = qrow0 + wstrip + mt * 16 + l15;
                *(f32x4*)(Pacc + ((size_t)(e * 2 + b) * NT + row) * 64 + ht * 16 + quad * 4) =
                    acc2[b][ht][mt];
            }
    // mask rowsums: sum the 4 quads' disjoint j ranges
#pragma unroll
    for (int mt = 0; mt < 2; mt++) {
        float v = rsl[mt];
        v += __shfl_xor(v, 16);
        v += __shfl_xor(v, 32);
        if (quad == 0)
            rsO[(size_t)e * NT + qrow0 + wstrip + mt * 16 + l15] = v;
    }
}

// ---------------------------------------------------------------------------
// Kernel 3: combine partials (acc_t = P_{2t}/rs_{2t} + P_{2t+1}/rs_{2t+1}),
// dt_t = 2*sigmoid(h_t Wdt_t^T + b) - 1, h_tn = h_t + step*dt*(u_t), outputs.
// Block: 256 thr, 64 rows. grid = 128.
// ---------------------------------------------------------------------------
__global__ __launch_bounds__(256) void update_kernel(
    const float* __restrict__ x0, const float* __restrict__ h0,
    const float* __restrict__ h1, const float* __restrict__ h2,
    const float* __restrict__ Wsu0, const float* __restrict__ Wsu12,
    const float* __restrict__ Wdt, const float* __restrict__ bdt,
    const float* __restrict__ stepp, const float* __restrict__ oscp,
    const float* __restrict__ Pacc, const float* __restrict__ rs,
    float* __restrict__ dout)
{
    const int tid = threadIdx.x, wid = tid >> 6, lane = tid & 63;
    const int l15 = lane & 15, quad = lane >> 4;
    const int g0 = blockIdx.x * 64;
    const int grow = g0 + wid * 16 + l15;
    const int n = grow & 4095, bb = grow >> 12;
    const float step = *stepp, osc = *oscp;
    const float* hs[3] = {h0, h1, h2};

    // A-fragments
    bf16x8 afh[3][2], afacc[3][2], afx;
#pragma unroll
    for (int t = 0; t < 3; t++)
#pragma unroll
        for (int hc = 0; hc < 2; hc++)
            afh[t][hc] = ld8f(hs[t] + (size_t)grow * 64 + hc * 32 + quad * 8);
    afx = ld8f(x0 + (size_t)grow * 32 + quad * 8);

#pragma unroll
    for (int t = 0; t < 3; t++) {
        float i0 = 1.f / rs[(size_t)(2 * t) * NT + n];
        float i1 = 1.f / rs[(size_t)(2 * t + 1) * NT + n];
#pragma unroll
        for (int hc = 0; hc < 2; hc++) {
            const float* p0 = Pacc + ((size_t)(4 * t + bb) * NT + n) * 64 + hc * 32 + quad * 8;
            const float* p1 = Pacc + ((size_t)(4 * t + 2 + bb) * NT + n) * 64 + hc * 32 + quad * 8;
            f32x4 a0 = *(const f32x4*)p0, a1 = *(const f32x4*)(p0 + 4);
            f32x4 b0 = *(const f32x4*)p1, b1 = *(const f32x4*)(p1 + 4);
            bf16x8 v;
            v[0] = (bf16)(a0[0] * i0 + b0[0] * i1);
            v[1] = (bf16)(a0[1] * i0 + b0[1] * i1);
            v[2] = (bf16)(a0[2] * i0 + b0[2] * i1);
            v[3] = (bf16)(a0[3] * i0 + b0[3] * i1);
            v[4] = (bf16)(a1[0] * i0 + b1[0] * i1);
            v[5] = (bf16)(a1[1] * i0 + b1[1] * i1);
            v[6] = (bf16)(a1[2] * i0 + b1[2] * i1);
            v[7] = (bf16)(a1[3] * i0 + b1[3] * i1);
            afacc[t][hc] = v;
        }
    }

    float bdtv[3][4];
#pragma unroll
    for (int t = 0; t < 3; t++)
#pragma unroll
        for (int it = 0; it < 4; it++)
            bdtv[t][it] = bdt[t * 64 + it * 16 + l15];

#pragma unroll
    for (int t = 0; t < 3; t++) {
#pragma unroll
        for (int it = 0; it < 4; it++) {
            f32x4 z = {0.f, 0.f, 0.f, 0.f};
            f32x4 u = {0.f, 0.f, 0.f, 0.f};
#pragma unroll
            for (int hc = 0; hc < 2; hc++) {
                bf16x8 wb = ld8f(Wdt + (size_t)t * 4096 + (size_t)(it * 16 + l15) * 64 + hc * 32 + quad * 8);
                z = __builtin_amdgcn_mfma_f32_16x16x32_bf16(afh[t][hc], wb, z, 0, 0, 0);
            }
            if (t == 0) {
                bf16x8 w0 = ld8f(Wsu0 + (size_t)(it * 16 + l15) * 96 + quad * 8);
                u = __builtin_amdgcn_mfma_f32_16x16x32_bf16(afx, w0, u, 0, 0, 0);
#pragma unroll
                for (int kc = 0; kc < 2; kc++) {
                    bf16x8 wk = ld8f(Wsu0 + (size_t)(it * 16 + l15) * 96 + 32 + kc * 32 + quad * 8);
                    u = __builtin_amdgcn_mfma_f32_16x16x32_bf16(afacc[0][kc], wk, u, 0, 0, 0);
                }
            } else {
#pragma unroll
                for (int kc = 0; kc < 2; kc++) {
                    bf16x8 wk = ld8f(Wsu12 + (size_t)(t - 1) * 4096 + (size_t)(it * 16 + l15) * 64 + kc * 32 + quad * 8);
                    u = __builtin_amdgcn_mfma_f32_16x16x32_bf16(afacc[t][kc], wk, u, 0, 0, 0);
                }
            }
            const int colg = it * 16 + l15;
#pragma unroll
            for (int r = 0; r < 4; r++) {
                int row = g0 + wid * 16 + quad * 4 + r;
                float zz = z[r] + bdtv[t][it];
                float dtv = 2.f / (1.f + __expf(-zz)) - 1.f;
                float hval = hs[t][(size_t)row * 64 + colg];
                float hn = hval + step * dtv * u[r];
                dout[65536 + (size_t)t * 524288 + (size_t)row * 64 + colg] = hn;
                if (t == 2 && colg < 8)
                    dout[(size_t)row * 8 + colg] = osc * hn;
            }
        }
    }
}

extern "C" void kernel_launch(void* const* d_in, const int* in_sizes, int n_in,
                              void* d_out, int out_size, void* d_ws, size_t ws_size,
                              hipStream_t stream) {
    const float* x0   = (const float*)d_in[0];
    const float* h0   = (const float*)d_in[1];
    const float* h1   = (const float*)d_in[2];
    const float* h2   = (const float*)d_in[3];
    const float* m00  = (const float*)d_in[4];
    const float* m20  = (const float*)d_in[5];
    const float* m01  = (const float*)d_in[6];
    const float* m11  = (const float*)d_in[7];
    const float* m12  = (const float*)d_in[8];
    const float* m22  = (const float*)d_in[9];
    const float* Wq   = (const float*)d_in[10];
    const float* Wk   = (const float*)d_in[11];
    const float* Wsu0 = (const float*)d_in[12];
    const float* Wsu12= (const float*)d_in[13];
    const float* Wdt  = (const float*)d_in[14];
    const float* bdt  = (const float*)d_in[15];
    const float* step = (const float*)d_in[16];
    const float* oscl = (const float*)d_in[17];

    // workspace layout (bf16 counts are elements)
    bf16* qn  = (bf16*)d_ws;                    // 3*2*4096*64 = 1,572,864
    bf16* kn  = qn + 1572864;                   // 6*2*4096*64 = 3,145,728
    bf16* vT  = kn + 3145728;                   // 3*2*64*4096 = 1,572,864
    float* Pacc = (float*)(vT + 1572864);       // 6*2*4096*64 = 3,145,728 floats
    float* rs   = Pacc + 3145728;               // 6*4096 floats
    // total = 25,264,128 bytes

    prep_kernel<<<128, 256, 0, stream>>>(h0, h1, h2, Wq, Wk, qn, kn, vT);
    attn_kernel<<<192, 256, 0, stream>>>(qn, kn, vT, m00, m20, m01, m11, m12, m22, Pacc, rs);
    update_kernel<<<128, 256, 0, stream>>>(x0, h0, h1, h2, Wsu0, Wsu12, Wdt, bdt,
                                           step, oscl, Pacc, rs, (float*)d_out);
}

// Round 2
// 519.772 us; speedup vs baseline: 1.1965x; 1.1965x over previous
//
#include <hip/hip_runtime.h>

typedef __bf16 bf16;
typedef bf16 bf16x8 __attribute__((ext_vector_type(8)));
typedef float f32x4 __attribute__((ext_vector_type(4)));
typedef unsigned int u32x4 __attribute__((ext_vector_type(4)));
typedef unsigned short u16x8 __attribute__((ext_vector_type(8)));
typedef unsigned int uint;

constexpr int NT = 4096;   // sequence length N
// H = 64, B = 2

__device__ __forceinline__ bf16x8 ld8f(const float* p) {
    f32x4 a = *(const f32x4*)p;
    f32x4 b = *(const f32x4*)(p + 4);
    bf16x8 v;
    v[0] = (bf16)a[0]; v[1] = (bf16)a[1]; v[2] = (bf16)a[2]; v[3] = (bf16)a[3];
    v[4] = (bf16)b[0]; v[5] = (bf16)b[1]; v[6] = (bf16)b[2]; v[7] = (bf16)b[3];
    return v;
}

__device__ __forceinline__ uint pack2(float a, float b) {
    unsigned short ua = __builtin_bit_cast(unsigned short, (bf16)a);
    unsigned short ub = __builtin_bit_cast(unsigned short, (bf16)b);
    return (uint)ua | ((uint)ub << 16);
}

// ---------------------------------------------------------------------------
// Kernel 1: projections q_t = norm(h_t @ Wq[t]^T), k_e = norm(h_pred @ Wk[e]^T)
// (bf16 out), plus vT[p][b][h][n] = bf16 transpose of h_p.
// grid = 128 rowtiles x 3 slices (slice 0: vT + q-proj; 1: k-proj 0-2; 2: k-proj 3-5).
// Block: 256 thr = 4 waves, 64 rows of B*N per block.
// ---------------------------------------------------------------------------
__global__ __launch_bounds__(256) void prep_kernel(
    const float* __restrict__ h0, const float* __restrict__ h1, const float* __restrict__ h2,
    const float* __restrict__ Wq, const float* __restrict__ Wk,
    bf16* __restrict__ qn, bf16* __restrict__ kn, bf16* __restrict__ vT)
{
    __shared__ __align__(16) unsigned short tlds[4][16][72];
    const int tid = threadIdx.x, wid = tid >> 6, lane = tid & 63;
    const int l15 = lane & 15, quad = lane >> 4;
    const int bx = blockIdx.x;
    const int rt = bx & 127, sl = bx >> 7;       // slice 0..2
    const int g0 = rt * 64;
    const int grow = g0 + wid * 16 + l15;        // A-frag row (global b*N+n)
    const float* hs[3] = {h0, h1, h2};

    // A-fragments: h rows in bf16 (also the vT payload)
    bf16x8 af[3][2];
#pragma unroll
    for (int p = 0; p < 3; p++)
#pragma unroll
        for (int hc = 0; hc < 2; hc++)
            af[p][hc] = ld8f(hs[p] + (size_t)grow * 64 + hc * 32 + quad * 8);

    // ---- slice 0 only: vT transpose via per-wave LDS tile ----
    if (sl == 0) {
        const int gr0 = g0 + wid * 16;
        const int bb = gr0 >> 12, n0 = gr0 & 4095;
#pragma unroll
        for (int p = 0; p < 3; p++) {
#pragma unroll
            for (int hc = 0; hc < 2; hc++)
                *(u16x8*)(&tlds[wid][l15][hc * 32 + quad * 8]) = __builtin_bit_cast(u16x8, af[p][hc]);
            unsigned short vals[16];
#pragma unroll
            for (int r = 0; r < 16; r++) vals[r] = tlds[wid][r][lane];
            uint us[8];
#pragma unroll
            for (int k = 0; k < 8; k++) us[k] = (uint)vals[2 * k] | ((uint)vals[2 * k + 1] << 16);
            uint* dst = (uint*)(vT + ((size_t)(p * 2 + bb) * 64 + lane) * NT + n0);
            u32x4 w0 = {us[0], us[1], us[2], us[3]};
            u32x4 w1 = {us[4], us[5], us[6], us[7]};
            *(u32x4*)dst = w0;
            *(u32x4*)(dst + 4) = w1;
        }
    }

    // ---- 3 projections per slice: slice0 -> q 0..2; slice1 -> k 0..2; slice2 -> k 3..5
    const int predmap[6] = {0, 2, 0, 1, 1, 2};
    const int pj0 = sl * 3;
#pragma unroll
    for (int pi = 0; pi < 3; pi++) {
        const int pj = pj0 + pi;
        const float* W = (pj < 3) ? (Wq + pj * 4096) : (Wk + (pj - 3) * 4096);
        const int src = (pj < 3) ? pj : predmap[pj - 3];
        bf16* outp = (pj < 3) ? (qn + (size_t)pj * 2 * NT * 64)
                              : (kn + (size_t)(pj - 3) * 2 * NT * 64);
        f32x4 s[4];
#pragma unroll
        for (int it = 0; it < 4; it++) {
            f32x4 acc = {0.f, 0.f, 0.f, 0.f};
#pragma unroll
            for (int hc = 0; hc < 2; hc++) {
                bf16x8 wb = ld8f(W + (size_t)(it * 16 + l15) * 64 + hc * 32 + quad * 8);
                acc = __builtin_amdgcn_mfma_f32_16x16x32_bf16(af[src][hc], wb, acc, 0, 0, 0);
            }
            s[it] = acc;
        }
        // row-wise normalization (fp32): row = quad*4 + r; reduce over 16 col-lanes
#pragma unroll
        for (int r = 0; r < 4; r++) {
            float ss = s[0][r] * s[0][r] + s[1][r] * s[1][r] + s[2][r] * s[2][r] + s[3][r] * s[3][r];
            ss += __shfl_xor(ss, 1); ss += __shfl_xor(ss, 2);
            ss += __shfl_xor(ss, 4); ss += __shfl_xor(ss, 8);
            float rn = rsqrtf(ss);
            s[0][r] *= rn; s[1][r] *= rn; s[2][r] *= rn; s[3][r] *= rn;
        }
        const int rowbase = g0 + wid * 16 + quad * 4;
#pragma unroll
        for (int it = 0; it < 4; it++)
#pragma unroll
            for (int r = 0; r < 4; r++)
                outp[(size_t)(rowbase + r) * 64 + it * 16 + l15] = (bf16)s[it][r];
    }
}

// ---------------------------------------------------------------------------
// Kernel 2: masked cosine attention, unscaled partials + mask rowsums,
// split into JC j-chunks for occupancy. grid = 6 edges * 32 q-tiles * JC.
// Block = 256 thr (4 waves * 32 q-rows); both batches per block so each mask
// byte is read exactly once. S^T = K·Q^T per 64-wide j tile; P^T = mask ⊙ S^T
// (bf16); acc^T += VT·P^T, B-frags built via ds_bpermute quad shuffle.
// ---------------------------------------------------------------------------
template<int JC>
__global__ __launch_bounds__(256, 3) void attn_kernel(
    const bf16* __restrict__ qn, const bf16* __restrict__ kn, const bf16* __restrict__ vT,
    const float* __restrict__ m00, const float* __restrict__ m20, const float* __restrict__ m01,
    const float* __restrict__ m11, const float* __restrict__ m12, const float* __restrict__ m22,
    float* __restrict__ Pacc, float* __restrict__ rsO)
{
    __shared__ __align__(16) bf16 Klds[2][64][72];
    __shared__ __align__(16) bf16 Vlds[2][64][72];
    const int tid = threadIdx.x, wid = tid >> 6, lane = tid & 63;
    const int l15 = lane & 15, quad = lane >> 4;
    const int bx = blockIdx.x;
    const int e = bx / (32 * JC);
    const int rem = bx % (32 * JC);
    const int qt = rem / JC, jcv = rem % JC;
    const int qrow0 = qt * 128, wstrip = wid * 32;
    const int qtypemap[6] = {0, 0, 1, 1, 2, 2};
    const int predmap[6]  = {0, 2, 0, 1, 1, 2};
    const float* masks[6] = {m00, m20, m01, m11, m12, m22};
    const float* __restrict__ mask = masks[e];
    const int qtv = qtypemap[e], pv = predmap[e];
    constexpr int JSPAN = NT / JC;
    const int jbeg = jcv * JSPAN, jend = jbeg + JSPAN;

    // Q fragments (stage-1 B-operand), register resident: [b][mt][hc]
    bf16x8 Qf[2][2][2];
#pragma unroll
    for (int b = 0; b < 2; b++)
#pragma unroll
        for (int mt = 0; mt < 2; mt++)
#pragma unroll
            for (int hc = 0; hc < 2; hc++)
                Qf[b][mt][hc] = *(const bf16x8*)(qn +
                    ((size_t)(qtv * 2 + b) * NT + qrow0 + wstrip + mt * 16 + l15) * 64 +
                    hc * 32 + quad * 8);

    f32x4 acc2[2][4][2];   // [b][ht][mt]  (acc^T: row=h, col=query)
#pragma unroll
    for (int b = 0; b < 2; b++)
#pragma unroll
        for (int ht = 0; ht < 4; ht++)
#pragma unroll
            for (int mt = 0; mt < 2; mt++) {
                f32x4 z = {0.f, 0.f, 0.f, 0.f};
                acc2[b][ht][mt] = z;
            }
    float rsl[2] = {0.f, 0.f};

#pragma unroll 1
    for (int j0 = jbeg; j0 < jend; j0 += 64) {
        __syncthreads();
        // stage K (kn rows) and VT (vT rows) for both batches
#pragma unroll
        for (int i = 0; i < 4; i++) {
            int u = tid + 256 * i;                 // 0..1023
            int b = u >> 9, jl = (u >> 3) & 63, ch = u & 7;
            *(u32x4*)(&Klds[b][jl][ch * 8]) =
                *(const u32x4*)(kn + ((size_t)(e * 2 + b) * NT + j0 + jl) * 64 + ch * 8);
            *(u32x4*)(&Vlds[b][jl][ch * 8]) =
                *(const u32x4*)(vT + ((size_t)(pv * 2 + b) * 64 + jl) * NT + j0 + ch * 8);
        }
        __syncthreads();

        // mask fragments (shared by both batches): rows=query m, 4 consecutive j per lane
        f32x4 mv[2][4];
#pragma unroll
        for (int mt = 0; mt < 2; mt++)
#pragma unroll
            for (int jt = 0; jt < 4; jt++) {
                mv[mt][jt] = *(const f32x4*)(mask +
                    (size_t)(qrow0 + wstrip + mt * 16 + l15) * NT + j0 + jt * 16 + quad * 4);
                rsl[mt] += mv[mt][jt][0] + mv[mt][jt][1] + mv[mt][jt][2] + mv[mt][jt][3];
            }

#pragma unroll
        for (int b = 0; b < 2; b++) {
            // stage 1: S^T tiles; pack masked result to bf16 pairs
            uint Pd[4][2][2];    // [jt][mt][d] ; d packs j-pair (quad*4+2d, +1)
#pragma unroll
            for (int jt = 0; jt < 4; jt++)
#pragma unroll
                for (int mt = 0; mt < 2; mt++) {
                    f32x4 sc = {0.f, 0.f, 0.f, 0.f};
#pragma unroll
                    for (int hc = 0; hc < 2; hc++) {
                        bf16x8 a = *(const bf16x8*)(&Klds[b][jt * 16 + l15][hc * 32 + quad * 8]);
                        sc = __builtin_amdgcn_mfma_f32_16x16x32_bf16(a, Qf[b][mt][hc], sc, 0, 0, 0);
                    }
                    sc[0] *= mv[mt][jt][0]; sc[1] *= mv[mt][jt][1];
                    sc[2] *= mv[mt][jt][2]; sc[3] *= mv[mt][jt][3];
                    Pd[jt][mt][0] = pack2(sc[0], sc[1]);
                    Pd[jt][mt][1] = pack2(sc[2], sc[3]);
                }

            // build stage-2 B-fragments (P^T) via ds_bpermute:
            // target (quad tq, col n) vgpr v holds j = c*32 + tq*8 + 2v..2v+1
            // source: tile jt = 2c + (tq>>1), lane quad = (tq&1)*2 + (v>>1), dword = v&1
            uint Bf[2][2][4];    // [mt][c][v]
#pragma unroll
            for (int mt = 0; mt < 2; mt++)
#pragma unroll
                for (int c = 0; c < 2; c++)
#pragma unroll
                    for (int v = 0; v < 4; v++) {
                        int srclane = ((((quad & 1) * 2 + (v >> 1)) * 16 + l15) << 2);
                        int lo = __builtin_amdgcn_ds_bpermute(srclane, (int)Pd[2 * c][mt][v & 1]);
                        int hi = __builtin_amdgcn_ds_bpermute(srclane, (int)Pd[2 * c + 1][mt][v & 1]);
                        Bf[mt][c][v] = (quad & 2) ? (uint)hi : (uint)lo;
                    }

            // stage 2: acc^T += VT · P^T
#pragma unroll
            for (int ht = 0; ht < 4; ht++)
#pragma unroll
                for (int c = 0; c < 2; c++) {
                    bf16x8 a = *(const bf16x8*)(&Vlds[b][ht * 16 + l15][c * 32 + quad * 8]);
#pragma unroll
                    for (int mt = 0; mt < 2; mt++) {
                        u32x4 t = {Bf[mt][c][0], Bf[mt][c][1], Bf[mt][c][2], Bf[mt][c][3]};
                        bf16x8 bbv = __builtin_bit_cast(bf16x8, t);
                        acc2[b][ht][mt] =
                            __builtin_amdgcn_mfma_f32_16x16x32_bf16(a, bbv, acc2[b][ht][mt], 0, 0, 0);
                    }
                }
        }
    }

    // store unscaled partials: acc^T C-layout -> rows n, 4 consecutive h per store
#pragma unroll
    for (int b = 0; b < 2; b++)
#pragma unroll
        for (int ht = 0; ht < 4; ht++)
#pragma unroll
            for (int mt = 0; mt < 2; mt++) {
                int row = qrow0 + wstrip + mt * 16 + l15;
                *(f32x4*)(Pacc + (((size_t)(jcv * 6 + e) * 2 + b) * NT + row) * 64 +
                          ht * 16 + quad * 4) = acc2[b][ht][mt];
            }
    // mask rowsums: sum the 4 quads' disjoint j ranges
#pragma unroll
    for (int mt = 0; mt < 2; mt++) {
        float v = rsl[mt];
        v += __shfl_xor(v, 16);
        v += __shfl_xor(v, 32);
        if (quad == 0)
            rsO[(size_t)(jcv * 6 + e) * NT + qrow0 + wstrip + mt * 16 + l15] = v;
    }
}

// ---------------------------------------------------------------------------
// Kernel 3: combine partials over JC chunks (acc_t = ΣP_{2t}/Σrs_{2t} + ...),
// dt_t = 2*sigmoid(h_t Wdt_t^T + b) - 1, h_tn = h_t + step*dt*u_t, outputs.
// grid = 128 rowtiles x 3 types. Block: 256 thr, 64 rows.
// ---------------------------------------------------------------------------
template<int JC>
__global__ __launch_bounds__(256) void update_kernel(
    const float* __restrict__ x0, const float* __restrict__ h0,
    const float* __restrict__ h1, const float* __restrict__ h2,
    const float* __restrict__ Wsu0, const float* __restrict__ Wsu12,
    const float* __restrict__ Wdt, const float* __restrict__ bdt,
    const float* __restrict__ stepp, const float* __restrict__ oscp,
    const float* __restrict__ Pacc, const float* __restrict__ rs,
    float* __restrict__ dout)
{
    const int tid = threadIdx.x, wid = tid >> 6, lane = tid & 63;
    const int l15 = lane & 15, quad = lane >> 4;
    const int bx = blockIdx.x;
    const int rt = bx & 127, t = bx >> 7;
    const int g0 = rt * 64;
    const int grow = g0 + wid * 16 + l15;
    const int n = grow & 4095, bb = grow >> 12;
    const float step = *stepp, osc = *oscp;
    const float* hs[3] = {h0, h1, h2};
    const float* __restrict__ ht_base = hs[t];

    // A-fragments
    bf16x8 afh[2], afacc[2], afx;
#pragma unroll
    for (int hc = 0; hc < 2; hc++)
        afh[hc] = ld8f(ht_base + (size_t)grow * 64 + hc * 32 + quad * 8);
    if (t == 0) afx = ld8f(x0 + (size_t)grow * 32 + quad * 8);

    // combine acc over JC chunks with row scaling
    float s0 = 0.f, s1 = 0.f;
#pragma unroll
    for (int jc = 0; jc < JC; jc++) {
        s0 += rs[(size_t)(jc * 6 + 2 * t) * NT + n];
        s1 += rs[(size_t)(jc * 6 + 2 * t + 1) * NT + n];
    }
    const float i0 = 1.f / s0, i1 = 1.f / s1;
#pragma unroll
    for (int hc = 0; hc < 2; hc++) {
        f32x4 A0 = {0.f,0.f,0.f,0.f}, A1 = {0.f,0.f,0.f,0.f};
        f32x4 B0 = {0.f,0.f,0.f,0.f}, B1 = {0.f,0.f,0.f,0.f};
#pragma unroll
        for (int jc = 0; jc < JC; jc++) {
            const float* p0 = Pacc + (((size_t)(jc * 6 + 2 * t) * 2 + bb) * NT + n) * 64 + hc * 32 + quad * 8;
            const float* p1 = Pacc + (((size_t)(jc * 6 + 2 * t + 1) * 2 + bb) * NT + n) * 64 + hc * 32 + quad * 8;
            A0 += *(const f32x4*)p0;       A1 += *(const f32x4*)(p0 + 4);
            B0 += *(const f32x4*)p1;       B1 += *(const f32x4*)(p1 + 4);
        }
        bf16x8 v;
        v[0] = (bf16)(A0[0] * i0 + B0[0] * i1);
        v[1] = (bf16)(A0[1] * i0 + B0[1] * i1);
        v[2] = (bf16)(A0[2] * i0 + B0[2] * i1);
        v[3] = (bf16)(A0[3] * i0 + B0[3] * i1);
        v[4] = (bf16)(A1[0] * i0 + B1[0] * i1);
        v[5] = (bf16)(A1[1] * i0 + B1[1] * i1);
        v[6] = (bf16)(A1[2] * i0 + B1[2] * i1);
        v[7] = (bf16)(A1[3] * i0 + B1[3] * i1);
        afacc[hc] = v;
    }

    float bdtv[4];
#pragma unroll
    for (int it = 0; it < 4; it++)
        bdtv[it] = bdt[t * 64 + it * 16 + l15];

#pragma unroll
    for (int it = 0; it < 4; it++) {
        f32x4 z = {0.f, 0.f, 0.f, 0.f};
        f32x4 u = {0.f, 0.f, 0.f, 0.f};
#pragma unroll
        for (int hc = 0; hc < 2; hc++) {
            bf16x8 wb = ld8f(Wdt + (size_t)t * 4096 + (size_t)(it * 16 + l15) * 64 + hc * 32 + quad * 8);
            z = __builtin_amdgcn_mfma_f32_16x16x32_bf16(afh[hc], wb, z, 0, 0, 0);
        }
        if (t == 0) {
            bf16x8 w0 = ld8f(Wsu0 + (size_t)(it * 16 + l15) * 96 + quad * 8);
            u = __builtin_amdgcn_mfma_f32_16x16x32_bf16(afx, w0, u, 0, 0, 0);
#pragma unroll
            for (int kc = 0; kc < 2; kc++) {
                bf16x8 wk = ld8f(Wsu0 + (size_t)(it * 16 + l15) * 96 + 32 + kc * 32 + quad * 8);
                u = __builtin_amdgcn_mfma_f32_16x16x32_bf16(afacc[kc], wk, u, 0, 0, 0);
            }
        } else {
#pragma unroll
            for (int kc = 0; kc < 2; kc++) {
                bf16x8 wk = ld8f(Wsu12 + (size_t)(t - 1) * 4096 + (size_t)(it * 16 + l15) * 64 + kc * 32 + quad * 8);
                u = __builtin_amdgcn_mfma_f32_16x16x32_bf16(afacc[kc], wk, u, 0, 0, 0);
            }
        }
        const int colg = it * 16 + l15;
#pragma unroll
        for (int r = 0; r < 4; r++) {
            int row = g0 + wid * 16 + quad * 4 + r;
            float zz = z[r] + bdtv[it];
            float dtv = 2.f / (1.f + __expf(-zz)) - 1.f;
            float hval = ht_base[(size_t)row * 64 + colg];
            float hn = hval + step * dtv * u[r];
            dout[65536 + (size_t)t * 524288 + (size_t)row * 64 + colg] = hn;
            if (t == 2 && colg < 8)
                dout[(size_t)row * 8 + colg] = osc * hn;
        }
    }
}

extern "C" void kernel_launch(void* const* d_in, const int* in_sizes, int n_in,
                              void* d_out, int out_size, void* d_ws, size_t ws_size,
                              hipStream_t stream) {
    const float* x0   = (const float*)d_in[0];
    const float* h0   = (const float*)d_in[1];
    const float* h1   = (const float*)d_in[2];
    const float* h2   = (const float*)d_in[3];
    const float* m00  = (const float*)d_in[4];
    const float* m20  = (const float*)d_in[5];
    const float* m01  = (const float*)d_in[6];
    const float* m11  = (const float*)d_in[7];
    const float* m12  = (const float*)d_in[8];
    const float* m22  = (const float*)d_in[9];
    const float* Wq   = (const float*)d_in[10];
    const float* Wk   = (const float*)d_in[11];
    const float* Wsu0 = (const float*)d_in[12];
    const float* Wsu12= (const float*)d_in[13];
    const float* Wdt  = (const float*)d_in[14];
    const float* bdt  = (const float*)d_in[15];
    const float* step = (const float*)d_in[16];
    const float* oscl = (const float*)d_in[17];

    // workspace layout (bf16 counts are elements)
    bf16* qn  = (bf16*)d_ws;                    // 3*2*4096*64 = 1,572,864
    bf16* kn  = qn + 1572864;                   // 6*2*4096*64 = 3,145,728
    bf16* vT  = kn + 3145728;                   // 3*2*64*4096 = 1,572,864
    float* Pacc = (float*)(vT + 1572864);       // JC*6*2*4096*64 floats
    // rs follows Pacc: JC*6*4096 floats

    // bf16 region = 12,582,912 B; per-chunk Pacc = 12,582,912 B; per-chunk rs = 98,304 B
    auto need = [](size_t jc) { return 12582912 + jc * 12582912 + jc * 98304; };
    const int JC = (ws_size >= need(4)) ? 4 : ((ws_size >= need(2)) ? 2 : 1);

    prep_kernel<<<384, 256, 0, stream>>>(h0, h1, h2, Wq, Wk, qn, kn, vT);

    if (JC == 4) {
        float* rs = Pacc + (size_t)4 * 3145728;
        attn_kernel<4><<<192 * 4, 256, 0, stream>>>(qn, kn, vT, m00, m20, m01, m11, m12, m22, Pacc, rs);
        update_kernel<4><<<384, 256, 0, stream>>>(x0, h0, h1, h2, Wsu0, Wsu12, Wdt, bdt,
                                                  step, oscl, Pacc, rs, (float*)d_out);
    } else if (JC == 2) {
        float* rs = Pacc + (size_t)2 * 3145728;
        attn_kernel<2><<<192 * 2, 256, 0, stream>>>(qn, kn, vT, m00, m20, m01, m11, m12, m22, Pacc, rs);
        update_kernel<2><<<384, 256, 0, stream>>>(x0, h0, h1, h2, Wsu0, Wsu12, Wdt, bdt,
                                                  step, oscl, Pacc, rs, (float*)d_out);
    } else {
        float* rs = Pacc + (size_t)1 * 3145728;
        attn_kernel<1><<<192, 256, 0, stream>>>(qn, kn, vT, m00, m20, m01, m11, m12, m22, Pacc, rs);
        update_kernel<1><<<384, 256, 0, stream>>>(x0, h0, h1, h2, Wsu0, Wsu12, Wdt, bdt,
                                                  step, oscl, Pacc, rs, (float*)d_out);
    }
}